// Round 1
// baseline (116.590 us; speedup 1.0000x reference)
//
#include <hip/hip_runtime.h>
#include <hip/hip_bf16.h>
#include <stdint.h>

#define DM 1024
#define NH 16
#define DKq 64
#define SS 2048

typedef __bf16 bf16x8 __attribute__((ext_vector_type(8)));
typedef float f32x4 __attribute__((ext_vector_type(4)));
typedef unsigned short u16x8 __attribute__((ext_vector_type(8)));

static __device__ __forceinline__ unsigned short f2bf(float f) {
  union { float f; unsigned u; } v; v.f = f;
  unsigned r = v.u + 0x7FFFu + ((v.u >> 16) & 1u);
  return (unsigned short)(r >> 16);
}

static __device__ __forceinline__ void gload_lds16(const void* g, void* l) {
  __builtin_amdgcn_global_load_lds((const __attribute__((address_space(1))) void*)g,
                                   (__attribute__((address_space(3))) void*)l, 16, 0, 0);
}

// ---- cast fp32 -> bf16, 8 elems/thread ----
__global__ void cast_x_kernel(const float* __restrict__ src, unsigned short* __restrict__ dst, int n8) {
  int i = blockIdx.x * blockDim.x + threadIdx.x;
  if (i >= n8) return;
  const float4* s = reinterpret_cast<const float4*>(src) + (size_t)i * 2;
  float4 a = s[0], b = s[1];
  u16x8 o;
  o[0]=f2bf(a.x); o[1]=f2bf(a.y); o[2]=f2bf(a.z); o[3]=f2bf(a.w);
  o[4]=f2bf(b.x); o[5]=f2bf(b.y); o[6]=f2bf(b.z); o[7]=f2bf(b.w);
  *reinterpret_cast<u16x8*>(dst + (size_t)i * 8) = o;
}

__global__ void cast_w_kernel(const float* __restrict__ wq, const float* __restrict__ wk,
                              const float* __restrict__ wv, unsigned short* __restrict__ dst, int n8) {
  int i = blockIdx.x * blockDim.x + threadIdx.x;
  if (i >= n8) return;
  int which = i >> 17;              // 1024*1024/8 = 131072 chunks per matrix
  int local = i & 131071;
  const float* s = (which == 0 ? wq : (which == 1 ? wk : wv)) + (size_t)local * 8;
  float4 a = *(const float4*)s, b = *(const float4*)(s + 4);
  u16x8 o;
  o[0]=f2bf(a.x); o[1]=f2bf(a.y); o[2]=f2bf(a.z); o[3]=f2bf(a.w);
  o[4]=f2bf(b.x); o[5]=f2bf(b.y); o[6]=f2bf(b.z); o[7]=f2bf(b.w);
  *reinterpret_cast<u16x8*>(dst + (size_t)i * 8) = o;
}

// ---- fused QKV projection: [4096,1024] @ [3072,1024]^T + bias -> q/k/v (bf16) ----
__launch_bounds__(256)
__global__ void proj_gemm(const unsigned short* __restrict__ X, const unsigned short* __restrict__ W3,
                          const float* __restrict__ bq, const float* __restrict__ bk,
                          const float* __restrict__ bv,
                          unsigned short* __restrict__ qb, unsigned short* __restrict__ kb,
                          unsigned short* __restrict__ vb) {
  __shared__ __align__(16) unsigned short Ab[128 * 32];
  __shared__ __align__(16) unsigned short Bb[128 * 32];
  const int m0 = blockIdx.x * 128, n0 = blockIdx.y * 128;
  const int tid = threadIdx.x;
  const int w = tid >> 6, lane = tid & 63;
  const int i16 = lane & 15, kg = lane >> 4;
  const int wr = w >> 1, wc = w & 1;

  // staging: thread t stages elems t*8.. (row = t/4, col = (t%4)*8); second issue rows +64
  const int arow = tid >> 2, acol = (tid & 3) * 8;
  const unsigned short* Xp = X + (size_t)(m0 + arow) * DM + acol;
  const unsigned short* Wp = W3 + (size_t)(n0 + arow) * DM + acol;
  char* AbC = (char*)Ab;
  char* BbC = (char*)Bb;

  const f32x4 fz = {0.f, 0.f, 0.f, 0.f};
  f32x4 acc[4][4];
#pragma unroll
  for (int m = 0; m < 4; ++m)
#pragma unroll
    for (int n = 0; n < 4; ++n) acc[m][n] = fz;

  for (int k0 = 0; k0 < DM; k0 += 32) {
    gload_lds16(Xp + k0,            AbC + w * 1024);
    gload_lds16(Xp + 64 * DM + k0,  AbC + 4096 + w * 1024);
    gload_lds16(Wp + k0,            BbC + w * 1024);
    gload_lds16(Wp + 64 * DM + k0,  BbC + 4096 + w * 1024);
    __syncthreads();
    bf16x8 af[4], bfr[4];
#pragma unroll
    for (int m = 0; m < 4; ++m)
      af[m] = *(const bf16x8*)(AbC + ((wr * 64 + m * 16 + i16) * 32 + kg * 8) * 2);
#pragma unroll
    for (int n = 0; n < 4; ++n)
      bfr[n] = *(const bf16x8*)(BbC + ((wc * 64 + n * 16 + i16) * 32 + kg * 8) * 2);
#pragma unroll
    for (int m = 0; m < 4; ++m)
#pragma unroll
      for (int n = 0; n < 4; ++n)
        acc[m][n] = __builtin_amdgcn_mfma_f32_16x16x32_bf16(af[m], bfr[n], acc[m][n], 0, 0, 0);
    __syncthreads();
  }

#pragma unroll
  for (int n = 0; n < 4; ++n) {
    int ncol = n0 + wc * 64 + n * 16 + i16;
    int which = ncol >> 10, nn = ncol & 1023;
    const float* bias = (which == 0) ? bq : (which == 1) ? bk : bv;
    float bsv = bias[nn];
    int h = nn >> 6, d = nn & 63;
    unsigned short* dst = (which == 0) ? qb : (which == 1) ? kb : vb;
#pragma unroll
    for (int m = 0; m < 4; ++m) {
      int rbase = m0 + wr * 64 + m * 16 + kg * 4;
#pragma unroll
      for (int e = 0; e < 4; ++e) {
        int r = rbase + e;
        int bI = r >> 11, s = r & 2047;
        dst[(((size_t)bI * NH + h) * SS + s) * DKq + d] = f2bf(acc[m][n][e] + bsv);
      }
    }
  }
}

// ---- transpose V [b,h,s,d] -> [b,h,d,s] via LDS 64x64 tile ----
__global__ void transpose_v(const unsigned short* __restrict__ vb, unsigned short* __restrict__ vt) {
  __shared__ __align__(16) unsigned short t[64][72];
  const int s0 = blockIdx.x * 64, h = blockIdx.y, b = blockIdx.z;
  const unsigned short* src = vb + ((size_t)b * NH + h) * SS * DKq;
  unsigned short* dst = vt + ((size_t)b * NH + h) * DKq * SS;
  const int tid = threadIdx.x;
  const int r = tid >> 2, c0 = (tid & 3) * 16;
  u16x8 v0 = *(const u16x8*)(src + (size_t)(s0 + r) * DKq + c0);
  u16x8 v1 = *(const u16x8*)(src + (size_t)(s0 + r) * DKq + c0 + 8);
#pragma unroll
  for (int e = 0; e < 8; ++e) { t[r][c0 + e] = v0[e]; t[r][c0 + 8 + e] = v1[e]; }
  __syncthreads();
  const int d = tid >> 2, sc = (tid & 3) * 16;
  u16x8 o0, o1;
#pragma unroll
  for (int e = 0; e < 8; ++e) { o0[e] = t[sc + e][d]; o1[e] = t[sc + 8 + e][d]; }
  *(u16x8*)(dst + (size_t)d * SS + s0 + sc) = o0;
  *(u16x8*)(dst + (size_t)d * SS + s0 + sc + 8) = o1;
}

// ---- attention: block = (b, h, 64 q-rows); 4 waves x 16 rows; raw-exp softmax ----
__launch_bounds__(256)
__global__ void attn_kernel(const unsigned short* __restrict__ qb, const unsigned short* __restrict__ kb,
                            const unsigned short* __restrict__ vt, float* __restrict__ out) {
  __shared__ __align__(16) unsigned short Kb[4096];      // 64 rows x 64 bf16, slot-swizzled
  __shared__ __align__(16) unsigned short Vb[4096];      // 64 d-rows x 64 bf16, slot-swizzled
  __shared__ __align__(16) unsigned short Pb[4][16 * 72];
  const int qt = blockIdx.x, h = blockIdx.y, b = blockIdx.z;
  const int tid = threadIdx.x, w = tid >> 6, lane = tid & 63;
  const int i16 = lane & 15, kg = lane >> 4;

  const unsigned short* qsrc = qb + (((size_t)b * NH + h) * SS + qt * 64 + w * 16) * DKq;
  bf16x8 aQ0 = *(const bf16x8*)(qsrc + i16 * DKq + kg * 8);
  bf16x8 aQ1 = *(const bf16x8*)(qsrc + i16 * DKq + 32 + kg * 8);

  const unsigned short* kbase = kb + ((size_t)b * NH + h) * SS * DKq;
  const unsigned short* vbase = vt + ((size_t)b * NH + h) * DKq * SS;

  // staging: chunk L covers row L/8, 16B slot L%8; source slot pre-swizzled so
  // LDS[row][slot] = global[row][slot ^ (row&7)]
  const int L0 = tid, L1 = 256 + tid;
  const int r0 = L0 >> 3, sl0 = (L0 & 7) ^ (r0 & 7);
  const int r1 = L1 >> 3, sl1 = (L1 & 7) ^ (r1 & 7);
  char* KbC = (char*)Kb;
  char* VbC = (char*)Vb;
  char* PbC = (char*)&Pb[w][0];

  const f32x4 fz = {0.f, 0.f, 0.f, 0.f};
  f32x4 oacc[4];
#pragma unroll
  for (int n = 0; n < 4; ++n) oacc[n] = fz;
  f32x4 dacc = fz;
  bf16x8 ones;
#pragma unroll
  for (int e = 0; e < 8; ++e) ones[e] = (__bf16)1.0f;

  for (int t = 0; t < SS / 64; ++t) {
    const int sK = t * 64;
    gload_lds16(kbase + (size_t)(sK + r0) * DKq + sl0 * 8, KbC + w * 1024);
    gload_lds16(kbase + (size_t)(sK + r1) * DKq + sl1 * 8, KbC + 4096 + w * 1024);
    gload_lds16(vbase + (size_t)r0 * SS + sK + sl0 * 8,    VbC + w * 1024);
    gload_lds16(vbase + (size_t)r1 * SS + sK + sl1 * 8,    VbC + 4096 + w * 1024);
    __syncthreads();

    // S = Q K^T, P = exp(S/8), write P (bf16) to padded LDS
#pragma unroll
    for (int n = 0; n < 4; ++n) {
      int rr = n * 16 + i16;
      bf16x8 b0 = *(const bf16x8*)(KbC + rr * 128 + ((kg ^ (rr & 7)) << 4));
      bf16x8 b1 = *(const bf16x8*)(KbC + rr * 128 + (((4 + kg) ^ (rr & 7)) << 4));
      f32x4 s = __builtin_amdgcn_mfma_f32_16x16x32_bf16(aQ0, b0, fz, 0, 0, 0);
      s = __builtin_amdgcn_mfma_f32_16x16x32_bf16(aQ1, b1, s, 0, 0, 0);
#pragma unroll
      for (int e = 0; e < 4; ++e) {
        float p = __expf(s[e] * 0.125f);
        Pb[w][(kg * 4 + e) * 72 + n * 16 + i16] = f2bf(p);
      }
    }
    __syncthreads();  // conservative: P visibility (intra-wave only; remove next round)

    // O += P V ; rowsum via MFMA against ones
#pragma unroll
    for (int ks = 0; ks < 2; ++ks) {
      bf16x8 aP = *(const bf16x8*)(PbC + i16 * 144 + ks * 64 + kg * 16);
      dacc = __builtin_amdgcn_mfma_f32_16x16x32_bf16(aP, ones, dacc, 0, 0, 0);
#pragma unroll
      for (int n = 0; n < 4; ++n) {
        int rr = n * 16 + i16;
        bf16x8 bv_ = *(const bf16x8*)(VbC + rr * 128 + ((((ks << 2) + kg) ^ (rr & 7)) << 4));
        oacc[n] = __builtin_amdgcn_mfma_f32_16x16x32_bf16(aP, bv_, oacc[n], 0, 0, 0);
      }
    }
    __syncthreads();
  }

  float* obase = out + ((size_t)b * SS + qt * 64 + w * 16) * DM + h * DKq;
#pragma unroll
  for (int e = 0; e < 4; ++e) {
    int r = kg * 4 + e;
    float inv = 1.0f / (dacc[e] + 1e-8f);
#pragma unroll
    for (int n = 0; n < 4; ++n)
      obase[(size_t)r * DM + n * 16 + i16] = oacc[n][e] * inv;
  }
}

extern "C" void kernel_launch(void* const* d_in, const int* in_sizes, int n_in,
                              void* d_out, int out_size, void* d_ws, size_t ws_size,
                              hipStream_t stream) {
  const float* Q  = (const float*)d_in[0];
  const float* Wq = (const float*)d_in[1];
  const float* bq = (const float*)d_in[2];
  const float* Wk = (const float*)d_in[3];
  const float* bk = (const float*)d_in[4];
  const float* Wv = (const float*)d_in[5];
  const float* bv = (const float*)d_in[6];
  char* ws = (char*)d_ws;
  const size_t MB = 1024 * 1024;
  unsigned short* Xbf = (unsigned short*)(ws);              // 8 MB (reused as vt after proj)
  unsigned short* W3  = (unsigned short*)(ws + 8 * MB);     // 6 MB
  unsigned short* qb  = (unsigned short*)(ws + 14 * MB);    // 8 MB
  unsigned short* kb  = (unsigned short*)(ws + 22 * MB);    // 8 MB
  unsigned short* vb  = (unsigned short*)(ws + 30 * MB);    // 8 MB -> total 38 MB
  unsigned short* vt  = Xbf;                                // alias: X dead after proj

  cast_x_kernel<<<2048, 256, 0, stream>>>(Q, Xbf, 4096 * 1024 / 8);
  cast_w_kernel<<<1536, 256, 0, stream>>>(Wq, Wk, Wv, W3, 3 * 1024 * 1024 / 8);
  proj_gemm<<<dim3(32, 24), 256, 0, stream>>>(Xbf, W3, bq, bk, bv, qb, kb, vb);
  transpose_v<<<dim3(32, 16, 2), 256, 0, stream>>>(vb, vt);
  attn_kernel<<<dim3(32, 16, 2), 256, 0, stream>>>(qb, kb, vt, (float*)d_out);
}

// Round 2
// 95.590 us; speedup vs baseline: 1.2197x; 1.2197x over previous
//
#include <hip/hip_runtime.h>
#include <hip/hip_bf16.h>
#include <stdint.h>

#define DM 1024
#define NH 16
#define DKq 64
#define SS 2048

// fold 1/sqrt(Dk)=1/8 and log2(e) into K so P = exp2(S) directly
#define SCALE_K 0.18033688011112042f

typedef __bf16 bf16x8 __attribute__((ext_vector_type(8)));
typedef __bf16 bf16x4 __attribute__((ext_vector_type(4)));
typedef float f32x4 __attribute__((ext_vector_type(4)));
typedef float f32x16 __attribute__((ext_vector_type(16)));
typedef unsigned short u16x8 __attribute__((ext_vector_type(8)));

static __device__ __forceinline__ unsigned short f2bf(float f) {
  union { float f; unsigned u; } v; v.f = f;
  unsigned r = v.u + 0x7FFFu + ((v.u >> 16) & 1u);
  return (unsigned short)(r >> 16);
}

static __device__ __forceinline__ float fexp2(float x) {
#if __has_builtin(__builtin_amdgcn_exp2f)
  return __builtin_amdgcn_exp2f(x);
#else
  float r; asm("v_exp_f32 %0, %1" : "=v"(r) : "v"(x)); return r;
#endif
}

static __device__ __forceinline__ void gload_lds16(const void* g, void* l) {
  __builtin_amdgcn_global_load_lds((const __attribute__((address_space(1))) void*)g,
                                   (__attribute__((address_space(3))) void*)l, 16, 0, 0);
}

// ---- fused casts: X fp32->bf16, W{q,k,v} fp32->bf16 (Wk scaled) ----
__global__ void cast_all(const float* __restrict__ Q, const float* __restrict__ wq,
                         const float* __restrict__ wk, const float* __restrict__ wv,
                         unsigned short* __restrict__ Xb, unsigned short* __restrict__ W3) {
  int i = blockIdx.x * blockDim.x + threadIdx.x;  // 0 .. 917503
  const int nX8 = 4096 * 1024 / 8;                // 524288
  if (i < nX8) {
    const float4* s = reinterpret_cast<const float4*>(Q) + (size_t)i * 2;
    float4 a = s[0], b = s[1];
    u16x8 o;
    o[0]=f2bf(a.x); o[1]=f2bf(a.y); o[2]=f2bf(a.z); o[3]=f2bf(a.w);
    o[4]=f2bf(b.x); o[5]=f2bf(b.y); o[6]=f2bf(b.z); o[7]=f2bf(b.w);
    *reinterpret_cast<u16x8*>(Xb + (size_t)i * 8) = o;
  } else {
    int j = i - nX8;                 // 0 .. 393215
    int which = j >> 17;             // 131072 chunks per matrix
    int local = j & 131071;
    float sc = (which == 1) ? SCALE_K : 1.0f;
    const float* s = (which == 0 ? wq : (which == 1 ? wk : wv)) + (size_t)local * 8;
    float4 a = *(const float4*)s, b = *(const float4*)(s + 4);
    u16x8 o;
    o[0]=f2bf(a.x*sc); o[1]=f2bf(a.y*sc); o[2]=f2bf(a.z*sc); o[3]=f2bf(a.w*sc);
    o[4]=f2bf(b.x*sc); o[5]=f2bf(b.y*sc); o[6]=f2bf(b.z*sc); o[7]=f2bf(b.w*sc);
    *reinterpret_cast<u16x8*>(W3 + (size_t)j * 8) = o;
  }
}

// ---- fused QKV projection: [4096,1024] @ [3072,1024]^T + bias -> q/k (bhsd) , v (bhds) ----
__launch_bounds__(256)
__global__ void proj_gemm(const unsigned short* __restrict__ X, const unsigned short* __restrict__ W3,
                          const float* __restrict__ bq, const float* __restrict__ bk,
                          const float* __restrict__ bv,
                          unsigned short* __restrict__ qb, unsigned short* __restrict__ kbuf,
                          unsigned short* __restrict__ vt) {
  __shared__ __align__(16) unsigned short Ab[128 * 32];
  __shared__ __align__(16) unsigned short Bb[128 * 32];
  const int m0 = blockIdx.x * 128, n0 = blockIdx.y * 128;
  const int tid = threadIdx.x;
  const int w = tid >> 6, lane = tid & 63;
  const int i16 = lane & 15, kg = lane >> 4;
  const int wr = w >> 1, wc = w & 1;

  const int arow = tid >> 2, acol = (tid & 3) * 8;
  const unsigned short* Xp = X + (size_t)(m0 + arow) * DM + acol;
  const unsigned short* Wp = W3 + (size_t)(n0 + arow) * DM + acol;
  char* AbC = (char*)Ab;
  char* BbC = (char*)Bb;

  const f32x4 fz = {0.f, 0.f, 0.f, 0.f};
  f32x4 acc[4][4];
#pragma unroll
  for (int m = 0; m < 4; ++m)
#pragma unroll
    for (int n = 0; n < 4; ++n) acc[m][n] = fz;

  for (int k0 = 0; k0 < DM; k0 += 32) {
    gload_lds16(Xp + k0,            AbC + w * 1024);
    gload_lds16(Xp + 64 * DM + k0,  AbC + 4096 + w * 1024);
    gload_lds16(Wp + k0,            BbC + w * 1024);
    gload_lds16(Wp + 64 * DM + k0,  BbC + 4096 + w * 1024);
    __syncthreads();
    bf16x8 af[4], bfr[4];
#pragma unroll
    for (int m = 0; m < 4; ++m)
      af[m] = *(const bf16x8*)(AbC + ((wr * 64 + m * 16 + i16) * 32 + kg * 8) * 2);
#pragma unroll
    for (int n = 0; n < 4; ++n)
      bfr[n] = *(const bf16x8*)(BbC + ((wc * 64 + n * 16 + i16) * 32 + kg * 8) * 2);
#pragma unroll
    for (int m = 0; m < 4; ++m)
#pragma unroll
      for (int n = 0; n < 4; ++n)
        acc[m][n] = __builtin_amdgcn_mfma_f32_16x16x32_bf16(af[m], bfr[n], acc[m][n], 0, 0, 0);
    __syncthreads();
  }

#pragma unroll
  for (int n = 0; n < 4; ++n) {
    int ncol = n0 + wc * 64 + n * 16 + i16;
    int which = ncol >> 10, nn = ncol & 1023;
    const float* bias = (which == 0) ? bq : (which == 1) ? bk : bv;
    float bsv = bias[nn];
    if (which == 1) bsv *= SCALE_K;
    int h = nn >> 6, d = nn & 63;
#pragma unroll
    for (int m = 0; m < 4; ++m) {
      int rbase = m0 + wr * 64 + m * 16 + kg * 4;
#pragma unroll
      for (int e = 0; e < 4; ++e) {
        int r = rbase + e;
        int bI = r >> 11, s = r & 2047;
        if (which == 2) {
          vt[(((size_t)bI * NH + h) * DKq + d) * SS + s] = f2bf(acc[m][n][e] + bsv);
        } else {
          unsigned short* dst = (which == 0) ? qb : kbuf;
          dst[(((size_t)bI * NH + h) * SS + s) * DKq + d] = f2bf(acc[m][n][e] + bsv);
        }
      }
    }
  }
}

// ---- attention v2: 32x32x16 swapped-operand, in-register P, 64 q/wave ----
// block = 128 thr (2 waves), covers 128 q rows; grid 512 (XCD-grouped decode)
__launch_bounds__(128, 1)
__global__ void attn2(const unsigned short* __restrict__ qb, const unsigned short* __restrict__ kbuf,
                      const unsigned short* __restrict__ vt, float* __restrict__ out) {
  __shared__ __align__(16) unsigned short KV[2][2][4096];  // [buf][K/V][64 rows x 64 elem]
  const int bid = blockIdx.x;
  const int work = (bid & 7) * 64 + (bid >> 3);   // XCD-grouped: each XCD owns 4 (b,h)
  const int qt = work & 15, h = (work >> 4) & 15, b = work >> 8;
  const int tid = threadIdx.x, w = tid >> 6, lane = tid & 63;
  const int l31 = lane & 31, hi = lane >> 5;

  const size_t bh = (size_t)b * NH + h;
  const unsigned short* qsrc = qb + (bh * SS + qt * 128 + w * 64) * DKq;
  const unsigned short* kbase = kbuf + bh * SS * DKq;
  const unsigned short* vbase = vt + bh * DKq * SS;

  // Q frags: B-operand of mfma(K,Q): lane holds Q[q = l31 (+32r)][kd = m*16 + hi*8 + j]
  bf16x8 Qf[2][4];
#pragma unroll
  for (int r = 0; r < 2; ++r)
#pragma unroll
    for (int m = 0; m < 4; ++m)
      Qf[r][m] = *(const bf16x8*)(qsrc + (size_t)(r * 32 + l31) * DKq + m * 16 + hi * 8);

  // staging: 512 chunks each for K and V, 4 per thread; 16B-slot source swizzle ^(row&7)
  const unsigned short* kp[4];
  const unsigned short* vp[4];
  int ldo[4];
#pragma unroll
  for (int i = 0; i < 4; ++i) {
    int c = i * 128 + tid;
    int row = c >> 3, sl = (c & 7) ^ (row & 7);
    kp[i] = kbase + (size_t)row * DKq + sl * 8;
    vp[i] = vbase + (size_t)row * SS + sl * 8;
    ldo[i] = c * 8;
  }

  const f32x16 z16 = {0,0,0,0,0,0,0,0,0,0,0,0,0,0,0,0};
  f32x16 oacc[2][2];
  oacc[0][0] = z16; oacc[0][1] = z16; oacc[1][0] = z16; oacc[1][1] = z16;
  float dsum[2] = {0.f, 0.f};

  // prologue: stage tile 0 into buf0
#pragma unroll
  for (int i = 0; i < 4; ++i) {
    gload_lds16(kp[i], &KV[0][0][ldo[i]]);
    gload_lds16(vp[i], &KV[0][1][ldo[i]]);
  }

  for (int t = 0; t < SS / 64; ++t) {
    const int cur = t & 1;
    __syncthreads();                       // stage(t) complete + prev readers done
    if (t < SS / 64 - 1) {
#pragma unroll
      for (int i = 0; i < 4; ++i) {
        gload_lds16(kp[i] + (size_t)(t + 1) * 64 * DKq, &KV[cur ^ 1][0][ldo[i]]);
        gload_lds16(vp[i] + (size_t)(t + 1) * 64,       &KV[cur ^ 1][1][ldo[i]]);
      }
    }
    const unsigned short* Kc = KV[cur][0];
    const unsigned short* Vc = KV[cur][1];

    // S^T = K . Q^T  (two 32-k blocks, two q-halves)
    f32x16 S[2][2];
    S[0][0] = z16; S[0][1] = z16; S[1][0] = z16; S[1][1] = z16;
#pragma unroll
    for (int kbk = 0; kbk < 2; ++kbk) {
      const int krow = kbk * 32 + l31;
      const int sw = krow & 7;
#pragma unroll
      for (int m = 0; m < 4; ++m) {
        bf16x8 af = *(const bf16x8*)(Kc + krow * 64 + (((2 * m + hi) ^ sw) * 8));
        S[0][kbk] = __builtin_amdgcn_mfma_f32_32x32x16_bf16(af, Qf[0][m], S[0][kbk], 0, 0, 0);
        S[1][kbk] = __builtin_amdgcn_mfma_f32_32x32x16_bf16(af, Qf[1][m], S[1][kbk], 0, 0, 0);
      }
    }

    // V^T frags (A-operand of PV), shared by both q-halves
    bf16x8 vf[2][2][2];
#pragma unroll
    for (int dblk = 0; dblk < 2; ++dblk) {
      const int d = dblk * 32 + l31;
      const int sw = d & 7;
#pragma unroll
      for (int kbk = 0; kbk < 2; ++kbk)
#pragma unroll
        for (int c2 = 0; c2 < 2; ++c2) {
          bf16x4 lo  = *(const bf16x4*)(Vc + d * 64 + (((4 * kbk + 2 * c2)     ^ sw) * 8) + hi * 4);
          bf16x4 hi4 = *(const bf16x4*)(Vc + d * 64 + (((4 * kbk + 2 * c2 + 1) ^ sw) * 8) + hi * 4);
          vf[dblk][kbk][c2] = __builtin_shufflevector(lo, hi4, 0, 1, 2, 3, 4, 5, 6, 7);
        }
    }

#pragma unroll
    for (int r = 0; r < 2; ++r) {
      float ds = 0.f;
#pragma unroll
      for (int kbk = 0; kbk < 2; ++kbk)
#pragma unroll
        for (int e = 0; e < 16; ++e) {
          float p = fexp2(S[r][kbk][e]);
          S[r][kbk][e] = p;
          ds += p;
        }
      dsum[r] += ds;
#pragma unroll
      for (int kbk = 0; kbk < 2; ++kbk)
#pragma unroll
        for (int c2 = 0; c2 < 2; ++c2) {
          bf16x8 pf;
#pragma unroll
          for (int j = 0; j < 8; ++j) pf[j] = (__bf16)S[r][kbk][8 * c2 + j];
          oacc[r][0] = __builtin_amdgcn_mfma_f32_32x32x16_bf16(vf[0][kbk][c2], pf, oacc[r][0], 0, 0, 0);
          oacc[r][1] = __builtin_amdgcn_mfma_f32_32x32x16_bf16(vf[1][kbk][c2], pf, oacc[r][1], 0, 0, 0);
        }
    }
  }

  // finalize: cross-half rowsum, normalize, store O^T fragments as float4s
#pragma unroll
  for (int r = 0; r < 2; ++r) {
    float tot = dsum[r] + __shfl_xor(dsum[r], 32);
    float inv = 1.0f / (tot + 1e-8f);
    float* ob = out + ((size_t)b * SS + qt * 128 + w * 64 + r * 32 + l31) * DM + h * DKq;
#pragma unroll
    for (int dblk = 0; dblk < 2; ++dblk)
#pragma unroll
      for (int g = 0; g < 4; ++g) {
        f32x4 v4 = { oacc[r][dblk][4 * g] * inv, oacc[r][dblk][4 * g + 1] * inv,
                     oacc[r][dblk][4 * g + 2] * inv, oacc[r][dblk][4 * g + 3] * inv };
        *(f32x4*)(ob + dblk * 32 + 8 * g + 4 * hi) = v4;
      }
  }
}

extern "C" void kernel_launch(void* const* d_in, const int* in_sizes, int n_in,
                              void* d_out, int out_size, void* d_ws, size_t ws_size,
                              hipStream_t stream) {
  const float* Q  = (const float*)d_in[0];
  const float* Wq = (const float*)d_in[1];
  const float* bq = (const float*)d_in[2];
  const float* Wk = (const float*)d_in[3];
  const float* bk = (const float*)d_in[4];
  const float* Wv = (const float*)d_in[5];
  const float* bv = (const float*)d_in[6];
  char* ws = (char*)d_ws;
  const size_t MB = 1024 * 1024;
  unsigned short* Xbf = (unsigned short*)(ws);              // 8 MB
  unsigned short* W3  = (unsigned short*)(ws + 8 * MB);     // 6 MB
  unsigned short* qb  = (unsigned short*)(ws + 14 * MB);    // 8 MB
  unsigned short* kb  = (unsigned short*)(ws + 22 * MB);    // 8 MB
  unsigned short* vt  = (unsigned short*)(ws + 30 * MB);    // 8 MB -> total 38 MB

  cast_all<<<3584, 256, 0, stream>>>(Q, Wq, Wk, Wv, Xbf, W3);
  proj_gemm<<<dim3(32, 24), 256, 0, stream>>>(Xbf, W3, bq, bk, bv, qb, kb, vt);
  attn2<<<512, 128, 0, stream>>>(qb, kb, vt, (float*)d_out);
}